// Round 9
// baseline (1374.021 us; speedup 1.0000x reference)
//
#include <hip/hip_runtime.h>
#include <hip/hip_bf16.h>
#include <math.h>

#define N_NODES 50000
#define N_EDGES 400000
#define NCHUNK 25000           // N_EDGES / 16
#define N_QUADS 12500          // N_NODES / 4
#define SCAN_TILES 49          // ceil(N_NODES/1024)
#define GRID_BLOCKS 512        // 2 blocks/CU x 256 CUs — co-residency by construction
#define NWAVES (GRID_BLOCKS * 4)
#define GSTRIDE (GRID_BLOCKS * 256)

typedef __attribute__((ext_vector_type(8))) short short8;
typedef __attribute__((ext_vector_type(4))) float f32x4;

__device__ __forceinline__ float bf16_to_f32(unsigned short v) {
  return __uint_as_float(((unsigned int)v) << 16);
}

struct Params {
  const float* x;
  const int* node_type;
  const int* ei;
  const float* ea;
  const float *W_lin0, *b_lin0, *W_root, *b_conv, *W_e1, *b_e1, *W_e2, *b_e2;
  const float *W_ih, *b_ih, *W_hh, *b_hh, *W_lin1, *b_lin1, *W_up, *b_up;
  const float *W_down, *b_down, *U_B, *V_B, *U_A, *V_A, *w_edge, *W_line,
      *b_line;
  float* out;
  unsigned int* he_sorted;
  unsigned short* m_bufh;
  int* src_sorted;
  float* M_B;
  float* M_A;
  int* degI;
  int* row_off;
  int* cur;
  int* tsum;
  int* bar_cnt;   // zeroed by host memset before launch
  int* bar_gen;   // generation counter — correct from ANY initial value
  float* res;
};

// Generation-based grid barrier. Device-scope atomics + fences handle
// cross-XCD L2 non-coherence (plain stores flushed by release, spinners
// invalidate via acquire). Safe for repeated use; works from any initial
// bar_gen (only bar_cnt must start at 0).
__device__ __forceinline__ void gbar(int* cnt, int* gen) {
  __syncthreads();
  if (threadIdx.x == 0) {
    __threadfence();
    int g = __hip_atomic_load(gen, __ATOMIC_RELAXED, __HIP_MEMORY_SCOPE_AGENT);
    int a = __hip_atomic_fetch_add(cnt, 1, __ATOMIC_ACQ_REL,
                                   __HIP_MEMORY_SCOPE_AGENT);
    if (a == GRID_BLOCKS - 1) {
      __hip_atomic_store(cnt, 0, __ATOMIC_RELAXED, __HIP_MEMORY_SCOPE_AGENT);
      __hip_atomic_store(gen, g + 1, __ATOMIC_RELEASE,
                         __HIP_MEMORY_SCOPE_AGENT);
    } else {
      while (__hip_atomic_load(gen, __ATOMIC_ACQUIRE,
                               __HIP_MEMORY_SCOPE_AGENT) == g) {
        __builtin_amdgcn_s_sleep(8);
      }
    }
    __threadfence();
  }
  __syncthreads();
}

// ---------------------------------------------------------------------------
// Persistent mega-kernel, 512 blocks (2/CU guaranteed by launch_bounds +
// LDS arithmetic: 9.3KB/block, VGPR<=256 at 2 waves/EU). Phases:
//   P0 : lin0, deg count (degI pre-zeroed by host memset), M_B/M_A collapse
//        (msg_C / w_node / W_lin are dead code: only out_edges is returned)
//   S1-3: hierarchical exclusive scan of degI -> row_off (+cur); per-tile
//        state (d0..d3, excl) carried in registers across barriers
//   S4 : slot assignment + sorted-edge materialization (src_sorted +
//        bf16 he fragments he_sorted) — edge phase then fully coalesced
//   3x : edge-MFMA (m_bufh, coalesced bf16) | bar | gather+GRU (in-place
//        out update; last iteration fuses tail + log_softmax -> res)
// ---------------------------------------------------------------------------
__global__ __launch_bounds__(256, 2) void mega_kernel(Params P) {
  const int t = threadIdx.x;
  const int b = blockIdx.x;
  const int gid0 = b * 256 + t;

  __shared__ float sW0[256], sb0[16], sW1[128], sb1[32];
  __shared__ float sWr[256], sWihT[768], sWhhT[768], sbg[112];
  __shared__ int sdata[256];

  // ---- LDS staging (persists across all phases) ----
  sW0[t] = P.W_lin0[t];
  if (t < 16) sb0[t] = P.b_lin0[t];
  if (t < 128) sW1[t] = P.W_e1[t];
  if (t < 32) sb1[t] = P.b_e1[t];
  sWr[t] = P.W_root[t];
  {
    int kk = t >> 4, dd = t & 15;
#pragma unroll
    for (int g = 0; g < 3; ++g) {
      sWihT[g * 256 + dd * 16 + kk] = P.W_ih[g * 256 + t];
      sWhhT[g * 256 + dd * 16 + kk] = P.W_hh[g * 256 + t];
    }
  }
  if (t < 16) sbg[t] = P.b_conv[t];
  else if (t < 64) sbg[t] = P.b_ih[t - 16];
  else if (t < 112) sbg[t] = P.b_hh[t - 64];
  __syncthreads();

  // ---- per-wave MFMA B-fragments (We2 + b_e2, bf16), live whole kernel ----
  const int lane = t & 63;
  const int q = lane >> 4, nn = lane & 15;
  const int p = q >> 1, dbase = (q & 1) * 8;
  short8 bfrag[17];
#pragma unroll
  for (int s = 0; s < 16; ++s) {
    int h = 2 * s + p;
    union { short8 v; __hip_bfloat162 b2[4]; } bf;
#pragma unroll
    for (int jj = 0; jj < 4; ++jj) {
      float2 w;
      w.x = P.W_e2[h * 256 + (dbase + 2 * jj) * 16 + nn];
      w.y = P.W_e2[h * 256 + (dbase + 2 * jj + 1) * 16 + nn];
      bf.b2[jj] = __float22bfloat162_rn(w);
    }
    bfrag[s] = bf.v;
  }
  {
    union { short8 v; __hip_bfloat162 b2[4]; } bf;
#pragma unroll
    for (int jj = 0; jj < 4; ++jj) {
      float2 w;
      if (q < 2) {
        w.x = P.b_e2[(dbase + 2 * jj) * 16 + nn];
        w.y = P.b_e2[(dbase + 2 * jj + 1) * 16 + nn];
      } else {
        w.x = 0.f; w.y = 0.f;
      }
      bf.b2[jj] = __float22bfloat162_rn(w);
    }
    bfrag[16] = bf.v;
  }

  // ================= P0: lin0 + deg count + M_B/M_A =================
  for (int n = gid0; n < N_NODES; n += GSTRIDE) {
    float xr[16];
#pragma unroll
    for (int d = 0; d < 16; ++d) xr[d] = P.x[n * 16 + d];
#pragma unroll
    for (int k = 0; k < 16; ++k) {
      float acc = sb0[k];
#pragma unroll
      for (int d = 0; d < 16; ++d) acc += xr[d] * sW0[d * 16 + k];
      P.out[n * 16 + k] = fmaxf(acc, 0.f);
    }
  }
  for (int e = gid0; e < N_EDGES; e += GSTRIDE)
    atomicAdd(&P.degI[P.ei[N_EDGES + e]], 1);
  {
    int gw = b * 4 + (t >> 6);
    if (gw < 272) {
      float partial = 0.f;
      if (gw < 256) {
        int i = gw >> 4, j = gw & 15;
#pragma unroll
        for (int r8 = 0; r8 < 8; ++r8) {
          int r = lane + 64 * r8;
          partial += P.U_B[i * 512 + r] * P.V_B[r * 16 + j];
        }
      } else {
        int a = (gw - 256) >> 2, bb = (gw - 256) & 3;
#pragma unroll
        for (int r8 = 0; r8 < 8; ++r8) {
          int r = lane + 64 * r8;
          partial += P.U_A[a * 512 + r] * P.V_A[r * 4 + bb];
        }
      }
#pragma unroll
      for (int off = 32; off > 0; off >>= 1)
        partial += __shfl_down(partial, off);
      if (lane == 0) {
        if (gw < 256) P.M_B[gw] = partial;
        else P.M_A[gw - 256] = partial;
      }
    }
  }
  gbar(P.bar_cnt, P.bar_gen);

  // ================= S1: in-tile scan (state kept in registers) ===========
  int d0 = 0, d1 = 0, d2 = 0, d3 = 0, excl = 0;
  if (b < SCAN_TILES) {
    int n0 = b * 1024 + t * 4;
    d0 = (n0 + 0 < N_NODES) ? P.degI[n0 + 0] : 0;
    d1 = (n0 + 1 < N_NODES) ? P.degI[n0 + 1] : 0;
    d2 = (n0 + 2 < N_NODES) ? P.degI[n0 + 2] : 0;
    d3 = (n0 + 3 < N_NODES) ? P.degI[n0 + 3] : 0;
    int tsum_t = d0 + d1 + d2 + d3;
    sdata[t] = tsum_t;
    __syncthreads();
    for (int off = 1; off < 256; off <<= 1) {
      int v = (t >= off) ? sdata[t - off] : 0;
      __syncthreads();
      sdata[t] += v;
      __syncthreads();
    }
    excl = sdata[t] - tsum_t;
    if (t == 255) P.tsum[b] = sdata[255];
  }
  gbar(P.bar_cnt, P.bar_gen);

  // ================= S2: scan tile totals (block 0, wave 0) ===============
  if (b == 0 && t < 64) {
    int v = (t < SCAN_TILES) ? P.tsum[t] : 0;
    int incl = v;
#pragma unroll
    for (int off = 1; off < 64; off <<= 1) {
      int u = __shfl_up(incl, off, 64);
      if (t >= off) incl += u;
    }
    if (t < SCAN_TILES) P.tsum[t] = incl - v;  // exclusive
  }
  gbar(P.bar_cnt, P.bar_gen);

  // ================= S3: write row_off + cur ==============================
  if (b < SCAN_TILES) {
    int n0 = b * 1024 + t * 4;
    int pre = P.tsum[b] + excl;
    if (n0 + 0 < N_NODES) { P.row_off[n0 + 0] = pre; P.cur[n0 + 0] = pre; }
    pre += d0;
    if (n0 + 1 < N_NODES) { P.row_off[n0 + 1] = pre; P.cur[n0 + 1] = pre; }
    pre += d1;
    if (n0 + 2 < N_NODES) { P.row_off[n0 + 2] = pre; P.cur[n0 + 2] = pre; }
    pre += d2;
    if (n0 + 3 < N_NODES) { P.row_off[n0 + 3] = pre; P.cur[n0 + 3] = pre; }
  }
  if (gid0 == 0) P.row_off[N_NODES] = N_EDGES;
  gbar(P.bar_cnt, P.bar_gen);

  // ===== S4: slot + sorted-edge materialization (src + bf16 he frags) =====
  for (int e = gid0; e < N_EDGES; e += GSTRIDE) {
    int dst = P.ei[N_EDGES + e];
    int s = atomicAdd(&P.cur[dst], 1);
    P.src_sorted[s] = P.ei[e];

    float4 v = ((const float4*)P.ea)[e];
    float h[32];
#pragma unroll
    for (int k = 0; k < 32; ++k) {
      float a = sb1[k] + v.x * sW1[k] + v.y * sW1[32 + k] + v.z * sW1[64 + k] +
                v.w * sW1[96 + k];
      h[k] = fmaxf(a, 0.f);
    }
    unsigned int u[16];
#pragma unroll
    for (int pp = 0; pp < 2; ++pp)
#pragma unroll
      for (int tt = 0; tt < 8; ++tt) {
        float2 pr;
        pr.x = h[4 * tt + pp];
        pr.y = h[4 * tt + 2 + pp];
        __hip_bfloat162 bb = __float22bfloat162_rn(pr);
        u[pp * 8 + tt] = *(unsigned int*)&bb;
      }
    uint4* dstp = (uint4*)(P.he_sorted + (size_t)s * 16);
#pragma unroll
    for (int qq = 0; qq < 4; ++qq)
      dstp[qq] =
          make_uint4(u[4 * qq], u[4 * qq + 1], u[4 * qq + 2], u[4 * qq + 3]);
  }
  gbar(P.bar_cnt, P.bar_gen);

  // ================= 3x message-passing iterations ========================
  const int gw = b * 4 + (t >> 6);
  for (int it = 0; it < 3; ++it) {
    // ---- edge phase: m[E,16] = Z[E,512] @ W2' via 16x16x32 bf16 MFMA ----
    for (int c = gw; c < NCHUNK; c += NWAVES) {
      int e = c * 16 + nn;
      int src = P.src_sorted[e];
      const uint4* hp = (const uint4*)(P.he_sorted + (size_t)e * 16 + p * 8);
      uint4 h0 = hp[0], h1 = hp[1];
      unsigned int heu[8] = {h0.x, h0.y, h0.z, h0.w, h1.x, h1.y, h1.z, h1.w};
      const float4* op = (const float4*)(P.out + src * 16 + dbase);
      float4 o0 = op[0], o1 = op[1];
      float o[8] = {o0.x, o0.y, o0.z, o0.w, o1.x, o1.y, o1.z, o1.w};

      f32x4 acc = {0.f, 0.f, 0.f, 0.f};
#pragma unroll
      for (int s = 0; s < 16; ++s) {
        unsigned int hw = heu[s >> 1];
        float he_s = __uint_as_float((s & 1) ? (hw & 0xffff0000u) : (hw << 16));
        union { short8 v; __hip_bfloat162 b2[4]; } af;
#pragma unroll
        for (int jj = 0; jj < 4; ++jj) {
          float2 pr;
          pr.x = he_s * o[2 * jj];
          pr.y = he_s * o[2 * jj + 1];
          af.b2[jj] = __float22bfloat162_rn(pr);
        }
        acc = __builtin_amdgcn_mfma_f32_16x16x32_bf16(af.v, bfrag[s], acc, 0, 0, 0);
      }
      {  // bias step
        union { short8 v; __hip_bfloat162 b2[4]; } af;
#pragma unroll
        for (int jj = 0; jj < 4; ++jj) {
          float2 pr;
          if (q < 2) { pr.x = o[2 * jj]; pr.y = o[2 * jj + 1]; }
          else { pr.x = 0.f; pr.y = 0.f; }
          af.b2[jj] = __float22bfloat162_rn(pr);
        }
        acc = __builtin_amdgcn_mfma_f32_16x16x32_bf16(af.v, bfrag[16], acc, 0, 0, 0);
      }

      // D row (q*4+r) = edge c*16+q*4+r; coalesced bf16 store (no scatter)
#pragma unroll
      for (int r = 0; r < 4; ++r) {
        __hip_bfloat16 w = __float2bfloat16(acc[r]);
        P.m_bufh[(size_t)(c * 16 + q * 4 + r) * 16 + nn] =
            *(unsigned short*)&w;
      }
    }
    gbar(P.bar_cnt, P.bar_gen);

    // ---- gather + GRU: each 16-lane subgroup owns one node ----
    const int do_final = (it == 2);
    for (int quad = gw; quad < N_QUADS; quad += NWAVES) {
      int n = quad * 4 + q;
      int k = nn;
      int s0 = P.row_off[n], s1 = P.row_off[n + 1];

      float aggk = 0.f;
      for (int j = s0; j < s1; ++j)
        aggk += bf16_to_f32(P.m_bufh[(size_t)j * 16 + k]);
      float sc = 1.f / fmaxf((float)(s1 - s0), 1.f);

      float hk = P.out[n * 16 + k];

      float mk = sbg[k] + aggk * sc;
#pragma unroll
      for (int d = 0; d < 16; ++d) mk += __shfl(hk, d, 16) * sWr[d * 16 + k];
      mk = fmaxf(mk, 0.f);

      float gir = sbg[16 + k], giz = sbg[32 + k], gin = sbg[48 + k];
      float ghr = sbg[64 + k], ghz = sbg[80 + k], ghn = sbg[96 + k];
#pragma unroll
      for (int d = 0; d < 16; ++d) {
        float md = __shfl(mk, d, 16);
        float hd = __shfl(hk, d, 16);
        gir += md * sWihT[d * 16 + k];
        giz += md * sWihT[256 + d * 16 + k];
        gin += md * sWihT[512 + d * 16 + k];
        ghr += hd * sWhhT[d * 16 + k];
        ghz += hd * sWhhT[256 + d * 16 + k];
        ghn += hd * sWhhT[512 + d * 16 + k];
      }
      float r = 1.f / (1.f + __expf(-(gir + ghr)));
      float z = 1.f / (1.f + __expf(-(giz + ghz)));
      float xn = gin + r * ghn;
      float ng = 1.f - 2.f / (__expf(2.f * xn) + 1.f);  // tanh, saturating
      float hnew = (1.f - z) * ng + z * hk;

      if (!do_final) {
        P.out[n * 16 + k] = hnew;
        continue;
      }

      // -------- fused tail (only out_edges branch is live) --------
      float p0 = hnew * P.W_lin1[k * 4 + 0];
      float p1 = hnew * P.W_lin1[k * 4 + 1];
      float p2 = hnew * P.W_lin1[k * 4 + 2];
      float p3 = hnew * P.W_lin1[k * 4 + 3];
#pragma unroll
      for (int msk = 1; msk < 16; msk <<= 1) {
        p0 += __shfl_xor(p0, msk, 16);
        p1 += __shfl_xor(p1, msk, 16);
        p2 += __shfl_xor(p2, msk, 16);
        p3 += __shfl_xor(p3, msk, 16);
      }
      float oe0 = fmaxf(p0 + P.b_lin1[0], 0.f);
      float oe1 = fmaxf(p1 + P.b_lin1[1], 0.f);
      float oe2 = fmaxf(p2 + P.b_lin1[2], 0.f);
      float oe3 = fmaxf(p3 + P.b_lin1[3], 0.f);

      bool ev = (P.node_type[n] == 2);
      float ock = ev ? (P.b_up[k] + oe0 * P.W_up[k] + oe1 * P.W_up[16 + k] +
                        oe2 * P.W_up[32 + k] + oe3 * P.W_up[48 + k])
                     : hnew;

      float msgBk = 0.f;
#pragma unroll
      for (int d = 0; d < 16; ++d)
        msgBk += __shfl(ock, d, 16) * P.M_B[d * 16 + k];
      msgBk = fmaxf(msgBk, 0.f);

      float q0 = msgBk * P.W_down[k * 4 + 0];
      float q1 = msgBk * P.W_down[k * 4 + 1];
      float q2 = msgBk * P.W_down[k * 4 + 2];
      float q3 = msgBk * P.W_down[k * 4 + 3];
#pragma unroll
      for (int msk = 1; msk < 16; msk <<= 1) {
        q0 += __shfl_xor(q0, msk, 16);
        q1 += __shfl_xor(q1, msk, 16);
        q2 += __shfl_xor(q2, msk, 16);
        q3 += __shfl_xor(q3, msk, 16);
      }
      float mtb0 = q0 + P.b_down[0], mtb1 = q1 + P.b_down[1];
      float mtb2 = q2 + P.b_down[2], mtb3 = q3 + P.b_down[3];

      const float* MA = P.M_A;
      float mta0 = fmaxf(oe0 * MA[0] + oe1 * MA[4] + oe2 * MA[8] + oe3 * MA[12], 0.f);
      float mta1 = fmaxf(oe0 * MA[1] + oe1 * MA[5] + oe2 * MA[9] + oe3 * MA[13], 0.f);
      float mta2 = fmaxf(oe0 * MA[2] + oe1 * MA[6] + oe2 * MA[10] + oe3 * MA[14], 0.f);
      float mta3 = fmaxf(oe0 * MA[3] + oe1 * MA[7] + oe2 * MA[11] + oe3 * MA[15], 0.f);

      float c0 = P.w_edge[0] * (mta0 * mtb0);
      float c1 = P.w_edge[1] * (mta1 * mtb1);
      float c2 = P.w_edge[2] * (mta2 * mtb2);
      float c3 = P.w_edge[3] * (mta3 * mtb3);

      const float* WL = P.W_line;
      float f0 = oe0 + fmaxf(P.b_line[0] + c0 * WL[0] + c1 * WL[4] + c2 * WL[8] + c3 * WL[12], 0.f);
      float f1 = oe1 + fmaxf(P.b_line[1] + c0 * WL[1] + c1 * WL[5] + c2 * WL[9] + c3 * WL[13], 0.f);
      float f2 = oe2 + fmaxf(P.b_line[2] + c0 * WL[2] + c1 * WL[6] + c2 * WL[10] + c3 * WL[14], 0.f);
      float f3 = oe3 + fmaxf(P.b_line[3] + c0 * WL[3] + c1 * WL[7] + c2 * WL[11] + c3 * WL[15], 0.f);

      float mx = fmaxf(fmaxf(f0, f1), fmaxf(f2, f3));
      float se = __expf(f0 - mx) + __expf(f1 - mx) + __expf(f2 - mx) +
                 __expf(f3 - mx);
      float lse = mx + __logf(se);
      if (k < 4) {
        float v = (k == 0) ? f0 : (k == 1) ? f1 : (k == 2) ? f2 : f3;
        P.res[n * 4 + k] = v - lse;
      }
    }
    if (it < 2) gbar(P.bar_cnt, P.bar_gen);
  }
}

// ---------------------------------------------------------------------------
extern "C" void kernel_launch(void* const* d_in, const int* in_sizes, int n_in,
                              void* d_out, int out_size, void* d_ws,
                              size_t ws_size, hipStream_t stream) {
  Params P;
  P.x       = (const float*)d_in[0];
  P.node_type = (const int*)d_in[1];
  P.ei      = (const int*)d_in[2];
  P.ea      = (const float*)d_in[3];
  P.W_lin0  = (const float*)d_in[4];
  P.b_lin0  = (const float*)d_in[5];
  P.W_root  = (const float*)d_in[6];
  P.b_conv  = (const float*)d_in[7];
  P.W_e1    = (const float*)d_in[8];
  P.b_e1    = (const float*)d_in[9];
  P.W_e2    = (const float*)d_in[10];
  P.b_e2    = (const float*)d_in[11];
  P.W_ih    = (const float*)d_in[12];
  P.b_ih    = (const float*)d_in[13];
  P.W_hh    = (const float*)d_in[14];
  P.b_hh    = (const float*)d_in[15];
  P.W_lin1  = (const float*)d_in[16];
  P.b_lin1  = (const float*)d_in[17];
  P.W_up    = (const float*)d_in[18];
  P.b_up    = (const float*)d_in[19];
  P.W_down  = (const float*)d_in[20];
  P.b_down  = (const float*)d_in[21];
  P.U_B     = (const float*)d_in[22];
  P.V_B     = (const float*)d_in[23];
  // d_in[24..25] U_C,V_C and d_in[28..30] w_node,W_lin,b_lin : dead code
  P.U_A     = (const float*)d_in[26];
  P.V_A     = (const float*)d_in[27];
  P.w_edge  = (const float*)d_in[31];
  P.W_line  = (const float*)d_in[32];
  P.b_line  = (const float*)d_in[33];

  float* ws    = (float*)d_ws;
  P.out        = ws;                                           // N*16 f32
  P.he_sorted  = (unsigned int*)(P.out + N_NODES * 16);        // E*16 u32
  P.m_bufh     = (unsigned short*)(P.he_sorted + (size_t)N_EDGES * 16);  // E*16
  P.src_sorted = (int*)(P.m_bufh + (size_t)N_EDGES * 16);      // E
  P.M_B        = (float*)(P.src_sorted + N_EDGES);             // 256
  P.M_A        = P.M_B + 256;                                  // 16
  P.row_off    = (int*)(P.M_A + 16);                           // N+4 (pad)
  P.cur        = P.row_off + N_NODES + 4;                      // N
  P.tsum       = P.cur + N_NODES;                              // 64
  // zeroed region: degI (N) + bar_cnt + bar_gen + pad
  P.degI       = P.tsum + 64;                                  // N
  P.bar_cnt    = P.degI + N_NODES;                             // 1
  P.bar_gen    = P.bar_cnt + 1;                                // 1
  P.res        = (float*)d_out;

  // zero degI + barrier state in one small memset (bar_cnt MUST be 0;
  // bar_gen value is irrelevant — generation-based barrier)
  hipMemsetAsync(P.degI, 0, (N_NODES + 64) * sizeof(int), stream);

  void* kp[] = {&P};
  (void)kp;
  mega_kernel<<<GRID_BLOCKS, 256, 0, stream>>>(P);
}

// Round 10
// 350.373 us; speedup vs baseline: 3.9216x; 3.9216x over previous
//
#include <hip/hip_runtime.h>
#include <hip/hip_bf16.h>
#include <math.h>

#define N_NODES 50000
#define N_EDGES 400000
#define NCHUNK 25000           // N_EDGES / 16
#define E_BLOCKS 1563          // ceil(N_EDGES/256)
#define PRE_BASE (E_BLOCKS - 68)
#define SCAN_TILE 1024
#define SCAN_BLOCKS 49         // ceil(N_NODES/1024)
#define EDGE_GRID 1563         // 6252 waves -> ~4 chunks/wave (TLP for gather)

typedef __attribute__((ext_vector_type(8))) short short8;
typedef __attribute__((ext_vector_type(4))) float f32x4;

__device__ __forceinline__ float bf16_to_f32(unsigned short v) {
  return __uint_as_float(((unsigned int)v) << 16);
}

// ---------------------------------------------------------------------------
// K0 (setup): lin0 -> out (ids < N), deg count (ids < E), M_B/M_A low-rank
// collapse on the last 68 blocks. (msg_C / w_node / W_lin are dead code:
// only out_edges reaches the returned log_softmax.)  [validated R8]
// ---------------------------------------------------------------------------
__global__ __launch_bounds__(256) void setup_kernel(
    const float* __restrict__ x, const float* __restrict__ W_lin0,
    const float* __restrict__ b_lin0, const int* __restrict__ ei,
    const float* __restrict__ U_B, const float* __restrict__ V_B,
    const float* __restrict__ U_A, const float* __restrict__ V_A,
    float* __restrict__ out, int* __restrict__ degI, float* __restrict__ M_B,
    float* __restrict__ M_A) {
  __shared__ float sW0[256];
  __shared__ float sb0[16];
  int t = threadIdx.x;
  sW0[t] = W_lin0[t];
  if (t < 16) sb0[t] = b_lin0[t];
  __syncthreads();

  int gid = blockIdx.x * 256 + t;

  if (gid < N_NODES) {  // lin0
    float xr[16];
#pragma unroll
    for (int d = 0; d < 16; ++d) xr[d] = x[gid * 16 + d];
#pragma unroll
    for (int k = 0; k < 16; ++k) {
      float acc = sb0[k];
#pragma unroll
      for (int d = 0; d < 16; ++d) acc += xr[d] * sW0[d * 16 + k];
      out[gid * 16 + k] = fmaxf(acc, 0.f);
    }
  }

  if (gid < N_EDGES) atomicAdd(&degI[ei[N_EDGES + gid]], 1);

  if (blockIdx.x >= PRE_BASE) {  // M_B / M_A
    int w = (blockIdx.x - PRE_BASE) * 4 + (t >> 6);
    int lane = t & 63;
    float partial = 0.f;
    if (w < 256) {
      int i = w >> 4, j = w & 15;
#pragma unroll
      for (int r8 = 0; r8 < 8; ++r8) {
        int r = lane + 64 * r8;
        partial += U_B[i * 512 + r] * V_B[r * 16 + j];
      }
    } else if (w < 272) {
      int a = (w - 256) >> 2, b = (w - 256) & 3;
#pragma unroll
      for (int r8 = 0; r8 < 8; ++r8) {
        int r = lane + 64 * r8;
        partial += U_A[a * 512 + r] * V_A[r * 4 + b];
      }
    }
#pragma unroll
    for (int off = 32; off > 0; off >>= 1) partial += __shfl_down(partial, off);
    if (lane == 0) {
      if (w < 256) M_B[w] = partial;
      else if (w < 272) M_A[w - 256] = partial;
    }
  }
}

// ---------------------------------------------------------------------------
// K1: single-dispatch exclusive scan of degI -> row_off (+cur), decoupled
// lookback.  [validated R5]
// ---------------------------------------------------------------------------
__global__ __launch_bounds__(256) void scan_kernel(
    const int* __restrict__ degI, int* ticket, int* st,
    int* __restrict__ row_off, int* __restrict__ cur) {
  __shared__ int sdata[256];
  __shared__ int s_tile;
  __shared__ int s_base;
  int t = threadIdx.x;
  if (t == 0) s_tile = atomicAdd(ticket, 1);
  __syncthreads();
  int tile = s_tile;
  int n0 = tile * SCAN_TILE + t * 4;

  int d0 = (n0 + 0 < N_NODES) ? degI[n0 + 0] : 0;
  int d1 = (n0 + 1 < N_NODES) ? degI[n0 + 1] : 0;
  int d2 = (n0 + 2 < N_NODES) ? degI[n0 + 2] : 0;
  int d3 = (n0 + 3 < N_NODES) ? degI[n0 + 3] : 0;
  int tsum = d0 + d1 + d2 + d3;
  sdata[t] = tsum;
  __syncthreads();
  for (int off = 1; off < 256; off <<= 1) {
    int v = (t >= off) ? sdata[t - off] : 0;
    __syncthreads();
    sdata[t] += v;
    __syncthreads();
  }
  int excl = sdata[t] - tsum;
  int agg = sdata[255];

  if (t == 0) {
    if (tile == 0) {
      atomicExch(&st[0], (agg << 2) | 2);
      s_base = 0;
    } else {
      atomicExch(&st[tile], (agg << 2) | 1);
      int run = 0, idx = tile - 1;
      while (true) {
        int w = atomicAdd(&st[idx], 0);
        int stt = w & 3;
        if (stt == 2) { run += (w >> 2); break; }
        if (stt == 1) { run += (w >> 2); --idx; }
      }
      atomicExch(&st[tile], ((run + agg) << 2) | 2);
      s_base = run;
    }
  }
  __syncthreads();

  int pre = s_base + excl;
  if (n0 + 0 < N_NODES) { row_off[n0 + 0] = pre; cur[n0 + 0] = pre; }
  pre += d0;
  if (n0 + 1 < N_NODES) { row_off[n0 + 1] = pre; cur[n0 + 1] = pre; }
  pre += d1;
  if (n0 + 2 < N_NODES) { row_off[n0 + 2] = pre; cur[n0 + 2] = pre; }
  pre += d2;
  if (n0 + 3 < N_NODES) { row_off[n0 + 3] = pre; cur[n0 + 3] = pre; }
  if (tile == SCAN_BLOCKS - 1 && t == 0) row_off[N_NODES] = N_EDGES;
}

// ---------------------------------------------------------------------------
// K2 (slot + sorted-edge materialization): per edge, dst-sorted slot s,
// write src_sorted[s] + bf16 he fragments he_sorted[s] (layout:
// he_sorted[s*16 + p*8 + tt] packs h=4tt+p lo / h=4tt+2+p hi). [validated R8]
// ---------------------------------------------------------------------------
__global__ __launch_bounds__(256) void slot_kernel(
    const int* __restrict__ ei, const float* __restrict__ ea,
    const float* __restrict__ We1, const float* __restrict__ be1,
    int* __restrict__ cur, int* __restrict__ src_sorted,
    unsigned int* __restrict__ he_sorted) {
  __shared__ float sW[128];
  __shared__ float sb[32];
  int t = threadIdx.x;
  if (t < 128) sW[t] = We1[t];
  if (t < 32) sb[t] = be1[t];
  __syncthreads();
  int e = blockIdx.x * 256 + t;
  if (e >= N_EDGES) return;
  int dst = ei[N_EDGES + e];
  int s = atomicAdd(&cur[dst], 1);
  src_sorted[s] = ei[e];

  float4 v = ((const float4*)ea)[e];
  float h[32];
#pragma unroll
  for (int k = 0; k < 32; ++k) {
    float a = sb[k] + v.x * sW[k] + v.y * sW[32 + k] + v.z * sW[64 + k] +
              v.w * sW[96 + k];
    h[k] = fmaxf(a, 0.f);
  }
  unsigned int u[16];
#pragma unroll
  for (int p = 0; p < 2; ++p)
#pragma unroll
    for (int tt = 0; tt < 8; ++tt) {
      float2 pr;
      pr.x = h[4 * tt + p];
      pr.y = h[4 * tt + 2 + p];
      __hip_bfloat162 b = __float22bfloat162_rn(pr);
      u[p * 8 + tt] = *(unsigned int*)&b;
    }
  uint4* dstp = (uint4*)(he_sorted + (size_t)s * 16);
#pragma unroll
  for (int qq = 0; qq < 4; ++qq)
    dstp[qq] = make_uint4(u[4 * qq], u[4 * qq + 1], u[4 * qq + 2], u[4 * qq + 3]);
}

// ---------------------------------------------------------------------------
// K3 (edge MFMA, sorted): m[E,16] = Z[E,512] @ W2' via 16x16x32 bf16 MFMA.
// Everything coalesced except the out[src] gather: he_sorted sequential,
// stores direct (edge order == dst-sorted order, no slot indirection).
// B-fragments (We2 + b_e2, bf16) in VGPRs once per wave.  [validated R9 body]
// ---------------------------------------------------------------------------
__global__ __launch_bounds__(256) void edge_kernel(
    const int* __restrict__ src_sorted,
    const unsigned int* __restrict__ he_sorted, const float* __restrict__ We2,
    const float* __restrict__ be2, const float* __restrict__ out,
    unsigned short* __restrict__ m_bufh) {
  const int lane = threadIdx.x & 63;
  const int q = lane >> 4, nn = lane & 15;
  const int p = q >> 1, dbase = (q & 1) * 8;

  short8 bfrag[17];
#pragma unroll
  for (int s = 0; s < 16; ++s) {
    int h = 2 * s + p;
    union { short8 v; __hip_bfloat162 b2[4]; } bf;
#pragma unroll
    for (int jj = 0; jj < 4; ++jj) {
      float2 w;
      w.x = We2[h * 256 + (dbase + 2 * jj) * 16 + nn];
      w.y = We2[h * 256 + (dbase + 2 * jj + 1) * 16 + nn];
      bf.b2[jj] = __float22bfloat162_rn(w);
    }
    bfrag[s] = bf.v;
  }
  {
    union { short8 v; __hip_bfloat162 b2[4]; } bf;
#pragma unroll
    for (int jj = 0; jj < 4; ++jj) {
      float2 w;
      if (q < 2) {
        w.x = be2[(dbase + 2 * jj) * 16 + nn];
        w.y = be2[(dbase + 2 * jj + 1) * 16 + nn];
      } else {
        w.x = 0.f; w.y = 0.f;
      }
      bf.b2[jj] = __float22bfloat162_rn(w);
    }
    bfrag[16] = bf.v;
  }

  int wave = blockIdx.x * 4 + (threadIdx.x >> 6);
  const int nw = EDGE_GRID * 4;
  for (int c = wave; c < NCHUNK; c += nw) {
    int e = c * 16 + nn;
    int src = src_sorted[e];
    const uint4* hp = (const uint4*)(he_sorted + (size_t)e * 16 + p * 8);
    uint4 h0 = hp[0], h1 = hp[1];
    unsigned int heu[8] = {h0.x, h0.y, h0.z, h0.w, h1.x, h1.y, h1.z, h1.w};
    const float4* op = (const float4*)(out + src * 16 + dbase);
    float4 o0 = op[0], o1 = op[1];
    float o[8] = {o0.x, o0.y, o0.z, o0.w, o1.x, o1.y, o1.z, o1.w};

    f32x4 acc = {0.f, 0.f, 0.f, 0.f};
#pragma unroll
    for (int s = 0; s < 16; ++s) {
      unsigned int hw = heu[s >> 1];
      float he_s = __uint_as_float((s & 1) ? (hw & 0xffff0000u) : (hw << 16));
      union { short8 v; __hip_bfloat162 b2[4]; } af;
#pragma unroll
      for (int jj = 0; jj < 4; ++jj) {
        float2 pr;
        pr.x = he_s * o[2 * jj];
        pr.y = he_s * o[2 * jj + 1];
        af.b2[jj] = __float22bfloat162_rn(pr);
      }
      acc = __builtin_amdgcn_mfma_f32_16x16x32_bf16(af.v, bfrag[s], acc, 0, 0, 0);
    }
    {  // bias step
      union { short8 v; __hip_bfloat162 b2[4]; } af;
#pragma unroll
      for (int jj = 0; jj < 4; ++jj) {
        float2 pr;
        if (q < 2) { pr.x = o[2 * jj]; pr.y = o[2 * jj + 1]; }
        else { pr.x = 0.f; pr.y = 0.f; }
        af.b2[jj] = __float22bfloat162_rn(pr);
      }
      acc = __builtin_amdgcn_mfma_f32_16x16x32_bf16(af.v, bfrag[16], acc, 0, 0, 0);
    }

    // D row (q*4+r) = edge c*16+q*4+r; direct coalesced bf16 stores
#pragma unroll
    for (int r = 0; r < 4; ++r) {
      __hip_bfloat16 w = __float2bfloat16(acc[r]);
      m_bufh[(size_t)(c * 16 + q * 4 + r) * 16 + nn] = *(unsigned short*)&w;
    }
  }
}

// ---------------------------------------------------------------------------
// K4 (fused gather + GRU [+ final tail on last iter]): 16 lanes per node.
// [validated R5]
// ---------------------------------------------------------------------------
__global__ __launch_bounds__(256) void gather_gru_kernel(
    const int* __restrict__ row_off, const unsigned short* __restrict__ m_bufh,
    const float* __restrict__ Wroot, const float* __restrict__ bconv,
    const float* __restrict__ Wih, const float* __restrict__ bih,
    const float* __restrict__ Whh, const float* __restrict__ bhh,
    float* __restrict__ out, int do_final, const int* __restrict__ node_type,
    const float* __restrict__ Wlin1, const float* __restrict__ blin1,
    const float* __restrict__ Wup, const float* __restrict__ bup,
    const float* __restrict__ Wdown, const float* __restrict__ bdown,
    const float* __restrict__ M_B, const float* __restrict__ M_A,
    const float* __restrict__ wedge, const float* __restrict__ Wline,
    const float* __restrict__ bline, float* __restrict__ res) {
  __shared__ float sWr[256];
  __shared__ float sWihT[768];  // [g*256 + d*16 + k] = Wih[(g*16+k)*16+d]
  __shared__ float sWhhT[768];
  __shared__ float sb[112];     // bconv[16] | bih[48] | bhh[48]
  int t = threadIdx.x;
  int kk = t >> 4, dd = t & 15;
  sWr[t] = Wroot[t];
#pragma unroll
  for (int g = 0; g < 3; ++g) {
    sWihT[g * 256 + dd * 16 + kk] = Wih[g * 256 + t];
    sWhhT[g * 256 + dd * 16 + kk] = Whh[g * 256 + t];
  }
  if (t < 16) sb[t] = bconv[t];
  else if (t < 64) sb[t] = bih[t - 16];
  else if (t < 112) sb[t] = bhh[t - 64];
  __syncthreads();

  int n = blockIdx.x * 16 + (t >> 4);
  int k = t & 15;
  int s0 = row_off[n], s1 = row_off[n + 1];

  float aggk = 0.f;
  for (int j = s0; j < s1; ++j) aggk += bf16_to_f32(m_bufh[(size_t)j * 16 + k]);
  float sc = 1.f / fmaxf((float)(s1 - s0), 1.f);

  float hk = out[n * 16 + k];

  float mk = sb[k] + aggk * sc;
#pragma unroll
  for (int d = 0; d < 16; ++d) mk += __shfl(hk, d, 16) * sWr[d * 16 + k];
  mk = fmaxf(mk, 0.f);

  float gir = sb[16 + k], giz = sb[32 + k], gin = sb[48 + k];
  float ghr = sb[64 + k], ghz = sb[80 + k], ghn = sb[96 + k];
#pragma unroll
  for (int d = 0; d < 16; ++d) {
    float md = __shfl(mk, d, 16);
    float hd = __shfl(hk, d, 16);
    gir += md * sWihT[d * 16 + k];
    giz += md * sWihT[256 + d * 16 + k];
    gin += md * sWihT[512 + d * 16 + k];
    ghr += hd * sWhhT[d * 16 + k];
    ghz += hd * sWhhT[256 + d * 16 + k];
    ghn += hd * sWhhT[512 + d * 16 + k];
  }
  float r = 1.f / (1.f + __expf(-(gir + ghr)));
  float z = 1.f / (1.f + __expf(-(giz + ghz)));
  float xn = gin + r * ghn;
  float ng = 1.f - 2.f / (__expf(2.f * xn) + 1.f);  // tanh, saturates safely
  float hnew = (1.f - z) * ng + z * hk;

  if (!do_final) {
    out[n * 16 + k] = hnew;
    return;
  }

  // ---- fused tail (reference post-loop; only out_edges branch is live) ----
  float p0 = hnew * Wlin1[k * 4 + 0];
  float p1 = hnew * Wlin1[k * 4 + 1];
  float p2 = hnew * Wlin1[k * 4 + 2];
  float p3 = hnew * Wlin1[k * 4 + 3];
#pragma unroll
  for (int msk = 1; msk < 16; msk <<= 1) {
    p0 += __shfl_xor(p0, msk, 16);
    p1 += __shfl_xor(p1, msk, 16);
    p2 += __shfl_xor(p2, msk, 16);
    p3 += __shfl_xor(p3, msk, 16);
  }
  float oe0 = fmaxf(p0 + blin1[0], 0.f);
  float oe1 = fmaxf(p1 + blin1[1], 0.f);
  float oe2 = fmaxf(p2 + blin1[2], 0.f);
  float oe3 = fmaxf(p3 + blin1[3], 0.f);

  bool ev = (node_type[n] == 2);
  float ock = ev ? (bup[k] + oe0 * Wup[k] + oe1 * Wup[16 + k] +
                    oe2 * Wup[32 + k] + oe3 * Wup[48 + k])
                 : hnew;

  float msgBk = 0.f;
#pragma unroll
  for (int d = 0; d < 16; ++d) msgBk += __shfl(ock, d, 16) * M_B[d * 16 + k];
  msgBk = fmaxf(msgBk, 0.f);

  float q0 = msgBk * Wdown[k * 4 + 0];
  float q1 = msgBk * Wdown[k * 4 + 1];
  float q2 = msgBk * Wdown[k * 4 + 2];
  float q3 = msgBk * Wdown[k * 4 + 3];
#pragma unroll
  for (int msk = 1; msk < 16; msk <<= 1) {
    q0 += __shfl_xor(q0, msk, 16);
    q1 += __shfl_xor(q1, msk, 16);
    q2 += __shfl_xor(q2, msk, 16);
    q3 += __shfl_xor(q3, msk, 16);
  }
  float mtb0 = q0 + bdown[0], mtb1 = q1 + bdown[1];
  float mtb2 = q2 + bdown[2], mtb3 = q3 + bdown[3];

  float mta0 = fmaxf(oe0 * M_A[0] + oe1 * M_A[4] + oe2 * M_A[8] + oe3 * M_A[12], 0.f);
  float mta1 = fmaxf(oe0 * M_A[1] + oe1 * M_A[5] + oe2 * M_A[9] + oe3 * M_A[13], 0.f);
  float mta2 = fmaxf(oe0 * M_A[2] + oe1 * M_A[6] + oe2 * M_A[10] + oe3 * M_A[14], 0.f);
  float mta3 = fmaxf(oe0 * M_A[3] + oe1 * M_A[7] + oe2 * M_A[11] + oe3 * M_A[15], 0.f);

  float c0 = wedge[0] * (mta0 * mtb0);
  float c1 = wedge[1] * (mta1 * mtb1);
  float c2 = wedge[2] * (mta2 * mtb2);
  float c3 = wedge[3] * (mta3 * mtb3);

  float f0 = oe0 + fmaxf(bline[0] + c0 * Wline[0] + c1 * Wline[4] + c2 * Wline[8] + c3 * Wline[12], 0.f);
  float f1 = oe1 + fmaxf(bline[1] + c0 * Wline[1] + c1 * Wline[5] + c2 * Wline[9] + c3 * Wline[13], 0.f);
  float f2 = oe2 + fmaxf(bline[2] + c0 * Wline[2] + c1 * Wline[6] + c2 * Wline[10] + c3 * Wline[14], 0.f);
  float f3 = oe3 + fmaxf(bline[3] + c0 * Wline[3] + c1 * Wline[7] + c2 * Wline[11] + c3 * Wline[15], 0.f);

  float mx = fmaxf(fmaxf(f0, f1), fmaxf(f2, f3));
  float se = __expf(f0 - mx) + __expf(f1 - mx) + __expf(f2 - mx) +
             __expf(f3 - mx);
  float lse = mx + __logf(se);
  if (k < 4) {
    float v = (k == 0) ? f0 : (k == 1) ? f1 : (k == 2) ? f2 : f3;
    res[n * 4 + k] = v - lse;
  }
}

// ---------------------------------------------------------------------------
extern "C" void kernel_launch(void* const* d_in, const int* in_sizes, int n_in,
                              void* d_out, int out_size, void* d_ws,
                              size_t ws_size, hipStream_t stream) {
  const float* x       = (const float*)d_in[0];
  const int* node_type = (const int*)d_in[1];
  const int* ei        = (const int*)d_in[2];
  const float* ea      = (const float*)d_in[3];
  const float* W_lin0  = (const float*)d_in[4];
  const float* b_lin0  = (const float*)d_in[5];
  const float* W_root  = (const float*)d_in[6];
  const float* b_conv  = (const float*)d_in[7];
  const float* W_e1    = (const float*)d_in[8];
  const float* b_e1    = (const float*)d_in[9];
  const float* W_e2    = (const float*)d_in[10];
  const float* b_e2    = (const float*)d_in[11];
  const float* W_ih    = (const float*)d_in[12];
  const float* b_ih    = (const float*)d_in[13];
  const float* W_hh    = (const float*)d_in[14];
  const float* b_hh    = (const float*)d_in[15];
  const float* W_lin1  = (const float*)d_in[16];
  const float* b_lin1  = (const float*)d_in[17];
  const float* W_up    = (const float*)d_in[18];
  const float* b_up    = (const float*)d_in[19];
  const float* W_down  = (const float*)d_in[20];
  const float* b_down  = (const float*)d_in[21];
  const float* U_B     = (const float*)d_in[22];
  const float* V_B     = (const float*)d_in[23];
  // d_in[24..25] U_C,V_C and d_in[28..30] w_node,W_lin,b_lin : dead code
  const float* U_A     = (const float*)d_in[26];
  const float* V_A     = (const float*)d_in[27];
  const float* w_edge  = (const float*)d_in[31];
  const float* W_line  = (const float*)d_in[32];
  const float* b_line  = (const float*)d_in[33];

  float* ws = (float*)d_ws;
  float* out = ws;                                          // N*16 f32
  unsigned int* he_sorted = (unsigned int*)(out + N_NODES * 16);  // E*16 u32
  unsigned short* m_bufh =
      (unsigned short*)(he_sorted + (size_t)N_EDGES * 16);  // E*16 u16
  int* src_sorted = (int*)(m_bufh + (size_t)N_EDGES * 16);  // E
  float* M_B = (float*)(src_sorted + N_EDGES);              // 256
  float* M_A = M_B + 256;                                   // 16
  int* row_off = (int*)(M_A + 16);                          // N+4 (pad)
  int* cur = row_off + N_NODES + 4;                         // N
  int* degI = cur + N_NODES;                                // N   (zeroed)
  int* ticket = degI + N_NODES;                             // 1   (zeroed)
  int* st = ticket + 1;                                     // 63  (zeroed)

  // zero degI + ticket + st in one memset
  hipMemsetAsync(degI, 0, (N_NODES + 64) * sizeof(int), stream);

  setup_kernel<<<E_BLOCKS, 256, 0, stream>>>(x, W_lin0, b_lin0, ei, U_B, V_B,
                                             U_A, V_A, out, degI, M_B, M_A);
  scan_kernel<<<SCAN_BLOCKS, 256, 0, stream>>>(degI, ticket, st, row_off, cur);
  slot_kernel<<<E_BLOCKS, 256, 0, stream>>>(ei, ea, W_e1, b_e1, cur, src_sorted,
                                            he_sorted);

  for (int it = 0; it < 3; ++it) {
    edge_kernel<<<EDGE_GRID, 256, 0, stream>>>(src_sorted, he_sorted, W_e2,
                                               b_e2, out, m_bufh);
    gather_gru_kernel<<<N_NODES / 16, 256, 0, stream>>>(
        row_off, m_bufh, W_root, b_conv, W_ih, b_ih, W_hh, b_hh, out,
        (it == 2) ? 1 : 0, node_type, W_lin1, b_lin1, W_up, b_up, W_down,
        b_down, M_B, M_A, w_edge, W_line, b_line, (float*)d_out);
  }
}